// Round 9
// baseline (224.946 us; speedup 1.0000x reference)
//
#include <hip/hip_runtime.h>
#include <hip/hip_bf16.h>

typedef __attribute__((ext_vector_type(8))) short short8;
typedef __attribute__((ext_vector_type(4))) float f32x4;

#define NT 65536

__device__ __forceinline__ unsigned short f2bf(float f) {
    union { float f; unsigned int u; } v; v.f = f;
    unsigned int u = v.u;
    unsigned int r = (u + 0x7fffu + ((u >> 16) & 1u)) >> 16;  // RNE
    return (unsigned short)r;
}

__device__ __forceinline__ unsigned int cvt_pk_bf16(float lo, float hi) {
    unsigned int r;
    asm("v_cvt_pk_bf16_f32 %0, %1, %2" : "=v"(r) : "v"(lo), "v"(hi));
    return r;
}

#define VMCNT12() asm volatile("s_waitcnt vmcnt(12)" ::: "memory")
#define VMCNT8()  asm volatile("s_waitcnt vmcnt(8)" ::: "memory")
#define VMCNT0()  asm volatile("s_waitcnt vmcnt(0)" ::: "memory")
#define BAR()     __builtin_amdgcn_s_barrier()
#define SB0()     __builtin_amdgcn_sched_barrier(0)

// ---------------- prep (all 3 sources): bf16 B panel + per-k params ----------------
// Panel row n: k16=n>>5, typ=(n>>4)&1, r=n&15 -> k=k16*16+r; typ0=w, typ1=beta.
// prm per source (5*256 f32): [0:256)=||w_k||^2, [256)=gam^2, [512)=eta^2, [768)=alpha, [1024)=sig^2
__global__ void prep_kernel(const float* __restrict__ w0, const float* __restrict__ b0,
                            const float* __restrict__ a0, const float* __restrict__ s0,
                            const float* __restrict__ e0, const float* __restrict__ g0,
                            const float* __restrict__ w1, const float* __restrict__ b1,
                            const float* __restrict__ a1, const float* __restrict__ s1,
                            const float* __restrict__ e1, const float* __restrict__ g1,
                            const float* __restrict__ w2, const float* __restrict__ b2,
                            const float* __restrict__ a2, const float* __restrict__ s2,
                            const float* __restrict__ e2, const float* __restrict__ g2,
                            unsigned short* __restrict__ bc, float* __restrict__ prmAll) {
    __shared__ float red[2];
    const int bx = blockIdx.x;
    const int s = bx >> 9;            // 0..2
    const int n = bx & 511;           // panel row
    const int P = 512 >> s;
    const float* w   = (s == 0) ? w0 : ((s == 1) ? w1 : w2);
    const float* bet = (s == 0) ? b0 : ((s == 1) ? b1 : b2);
    const float* alp = (s == 0) ? a0 : ((s == 1) ? a1 : a2);
    const float* sig = (s == 0) ? s0 : ((s == 1) ? s1 : s2);
    const float* eta = (s == 0) ? e0 : ((s == 1) ? e1 : e2);
    const float* gam = (s == 0) ? g0 : ((s == 1) ? g1 : g2);
    unsigned short* dstb = bc + ((s == 0) ? 0 : ((s == 1) ? (512 * 512) : (512 * 512 + 512 * 256)));
    float* prm = prmAll + 1280 * s;

    const int tid = threadIdx.x;      // 128
    const int k16 = n >> 5;
    const int typ = (n >> 4) & 1;
    const int k = k16 * 16 + (n & 15);
    const bool isw = (typ == 0);
    const float* src = (isw ? w : bet) + (size_t)k * P;
    unsigned short* dst = dstb + (size_t)n * P;
    float ss = 0.f;
    for (int c = tid; c < P; c += 128) {
        float f = src[c];
        dst[c] = f2bf(f);
        if (isw) ss += f * f;
    }
#pragma unroll
    for (int m = 1; m < 64; m <<= 1) ss += __shfl_xor(ss, m);
    if ((tid & 63) == 0) red[tid >> 6] = ss;
    __syncthreads();
    if (isw && tid == 0) prm[k] = red[0] + red[1];
    if (n == 0) {
        for (int kk = tid; kk < 256; kk += 128) {
            float g = gam[kk], e = eta[kk];
            prm[256 + kk]  = g * g;
            prm[512 + kk]  = e * e;
            prm[768 + kk]  = alp[kk];
            prm[1024 + kk] = sig[kk] * sig[kk];
        }
    }
}

// ---------------- fused per-source: DMA-ring streaming GEMM + RBF epilogue ----------------
// grid 2048, 256 thr (4 waves 2(wp=panel)x2(wx=xrows)). Block: 128 panel-rows (pt) x 128
// x-rows (xt), BK=32, NK=P/32. Grid swizzle: xt=(b>>5)*8+(b&7), pt=(b>>3)&3 -> pt-siblings
// share an XCD (L2/L3 dedup of x).
// x staged as FP32 by global_load_lds into a 3-slot LDS ring (16 KB/slot), issue distance 2.
// cvt fp32->bf16 happens IN-REGISTER inside compute (no bf16 LDS, no write phase).
// B fragments come straight from L2 (global_load_dwordx4 per-lane gather, 16 full 64B
// lines per op) into a 2-set register ping-pong (issue distance 1).
// Per step: ONE barrier + ONE counted vmcnt (12 steady / 8 / 0 tail). Fully unrolled.
// fp32 LDS chunks XOR-swizzled: phys16B = c ^ (row&7) -> 2-way max (free).
// Swapped MFMA mfma(panel,x): k is lane-local -> epilogue = reg adds + 2 shuffles.
template<int P>
__global__ __launch_bounds__(256, 3)
void fused_src(const float* __restrict__ x, const unsigned short* __restrict__ Bc,
               const float* __restrict__ prm, float* __restrict__ pwsS) {
    constexpr int NK = P / 32;
    __shared__ float Xs[3][128 * 32];    // 48 KB fp32 ring
    __shared__ float xn2[128];

    const int b = blockIdx.x;
    const int xt = (b >> 5) * 8 + (b & 7);
    const int pt = (b >> 3) & 3;

    const int tid = threadIdx.x, lane = tid & 63, wv = tid >> 6;
    const int wp = wv >> 1, wx = wv & 1;
    const int l15 = lane & 15, l4 = lane >> 4;

    f32x4 acc[4][4];
#pragma unroll
    for (int pf = 0; pf < 4; pf++)
#pragma unroll
        for (int xf = 0; xf < 4; xf++) acc[pf][xf] = (f32x4){0.f, 0.f, 0.f, 0.f};

    // B fragment base pointers (per pf): row = pt*128 + 64*wp + 16*pf + l15, k-off = l4*8
    const unsigned short* afp[4];
#pragma unroll
    for (int pf = 0; pf < 4; pf++)
        afp[pf] = Bc + (size_t)(pt * 128 + 64 * wp + 16 * pf + l15) * P + l4 * 8;

    short8 bg[2][4];     // B-frag ping-pong (static indices after unroll)
    float ssx[4] = {0.f, 0.f, 0.f, 0.f};

    auto bgload = [&](int set, int t) {
#pragma unroll
        for (int pf = 0; pf < 4; pf++)
            bg[set][pf] = *(const short8*)(afp[pf] + t * 32);
    };
    auto dmaX = [&](int slot, int t) {
#pragma unroll
        for (int i = 0; i < 4; i++) {
            const int u = i * 256 + tid;
            const int row = u >> 3;
            const int c = u & 7;
            const float* src = x + (size_t)(xt * 128 + row) * P + t * 32 + ((c ^ (row & 7)) << 2);
            __builtin_amdgcn_global_load_lds((const __attribute__((address_space(1))) void*)src,
                (__attribute__((address_space(3))) void*)((char*)&Xs[slot][0] + u * 16), 16, 0, 0);
        }
    };
    auto compute = [&](int slot, int set) {
        short8 bf[4];
#pragma unroll
        for (int xf = 0; xf < 4; xf++) {
            const int row = 64 * wx + 16 * xf + l15;
            const float* base = &Xs[slot][row * 32];
            const int sw = row & 7;
            float4 q0 = *(const float4*)(base + (((l4 * 2) ^ sw) << 2));
            float4 q1 = *(const float4*)(base + (((l4 * 2 + 1) ^ sw) << 2));
            if (wp == 0)
                ssx[xf] += q0.x*q0.x + q0.y*q0.y + q0.z*q0.z + q0.w*q0.w
                         + q1.x*q1.x + q1.y*q1.y + q1.z*q1.z + q1.w*q1.w;
            uint4 pk = { cvt_pk_bf16(q0.x, q0.y), cvt_pk_bf16(q0.z, q0.w),
                         cvt_pk_bf16(q1.x, q1.y), cvt_pk_bf16(q1.z, q1.w) };
            bf[xf] = *(short8*)&pk;
        }
#pragma unroll
        for (int pf = 0; pf < 4; pf++)
#pragma unroll
            for (int xf = 0; xf < 4; xf++)
                acc[pf][xf] = __builtin_amdgcn_mfma_f32_16x16x32_bf16(bg[set][pf], bf[xf], acc[pf][xf], 0, 0, 0);
    };

    // ---- prologue: Bg(0), then DMA(0), DMA(1) (retire order: Bg0 first) ----
    bgload(0, 0); SB0();
    dmaX(0, 0);
    if (NK > 1) dmaX(1, 1);
    SB0();

    // ---- main loop: one barrier + one counted vmcnt per step ----
#pragma unroll
    for (int t = 0; t < NK; t++) {
        BAR(); SB0();
        if (t + 1 < NK) { bgload((t + 1) & 1, t + 1); SB0(); }
        if (t + 2 < NK) { dmaX((t + 2) % 3, t + 2); SB0(); }
        if (t + 2 < NK)      { VMCNT12(); }
        else if (t + 1 < NK) { VMCNT8();  }
        else                 { VMCNT0();  }
        SB0();
        compute(t % 3, t & 1);
        SB0();
    }

    // ---- ||x||^2 finalize: ssx[xf] lives on wp==0 waves; reduce over l4 (lane bits 4,5) ----
    if (wp == 0) {
#pragma unroll
        for (int xf = 0; xf < 4; xf++) {
            float v = ssx[xf];
            v += __shfl_xor(v, 16);
            v += __shfl_xor(v, 32);
            if (l4 == 0) xn2[64 * wx + 16 * xf + l15] = v;
        }
    }
    __syncthreads();

    // ---- epilogue: lane holds panel-row = pt*128+64wp+16pf+(4l4+j), x-row = 64wx+16xf+l15
    // pf = 2K+typ: typ0=w-dot, typ1=beta-dot, k = (pt*4+2wp+K)*16 + 4l4+j (lane-local)
    const int kb0 = (pt * 4 + 2 * wp) * 16 + 4 * l4;
    f32x4 wn2[2], g2[2], hv[2], alv[2], s2v[2];
#pragma unroll
    for (int K = 0; K < 2; K++) {
        const int kk = kb0 + 16 * K;
        wn2[K] = *(const f32x4*)(prm + kk);
        g2[K]  = *(const f32x4*)(prm + 256 + kk);
        hv[K]  = *(const f32x4*)(prm + 512 + kk);
        alv[K] = *(const f32x4*)(prm + 768 + kk);
        s2v[K] = *(const f32x4*)(prm + 1024 + kk);
    }
    float (*part)[128][3] = (float (*)[128][3])(&Xs[0][0]);   // alias dead ring
#pragma unroll
    for (int xf = 0; xf < 4; xf++) {
        const int xrow = 64 * wx + 16 * xf + l15;
        const float xv = xn2[xrow];
        float hs = 0.f, ms = 0.f, gs = 0.f;
#pragma unroll
        for (int K = 0; K < 2; K++) {
#pragma unroll
            for (int j = 0; j < 4; j++) {
                const float aw = acc[2 * K][xf][j];
                const float ab = acc[2 * K + 1][xf][j];
                const float d2 = xv - 2.f * aw + wn2[K][j];
                const float a  = __expf(-g2[K][j] * d2);
                const float ah = a * hv[K][j];
                hs += ah;
                ms += (ab + alv[K][j]) * ah;
                gs += s2v[K][j] * ah * ah;
            }
        }
        hs += __shfl_xor(hs, 16); hs += __shfl_xor(hs, 32);
        ms += __shfl_xor(ms, 16); ms += __shfl_xor(ms, 32);
        gs += __shfl_xor(gs, 16); gs += __shfl_xor(gs, 32);
        if (l4 == 0) {
            part[wp][xrow][0] = hs;
            part[wp][xrow][1] = ms;
            part[wp][xrow][2] = gs;
        }
    }
    __syncthreads();
    if (tid < 128) {
        const int gr = xt * 128 + tid;
#pragma unroll
        for (int v = 0; v < 3; v++)
            pwsS[(size_t)(pt * 3 + v) * NT + gr] = part[0][tid][v] + part[1][tid][v];
    }
}

// ---------------- combine: all outputs from 4 pt-partials per source ----------------
__global__ void combine_kernel(const float* __restrict__ pws,
                               const float* __restrict__ d0, const float* __restrict__ d1,
                               const float* __restrict__ d2, float* __restrict__ out) {
    const int t = blockIdx.x * 256 + threadIdx.x;
    float mux[3], s2x[3], hx[3];
#pragma unroll
    for (int s = 0; s < 3; s++) {
        const float* bbase = pws + (size_t)s * 12 * NT;
        float hh = 0.f, mm = 0.f, gg = 0.f;
#pragma unroll
        for (int pt = 0; pt < 4; pt++) {
            hh += bbase[(size_t)(pt * 3 + 0) * NT + t];
            mm += bbase[(size_t)(pt * 3 + 1) * NT + t];
            gg += bbase[(size_t)(pt * 3 + 2) * NT + t];
        }
        mux[s] = mm / hh; s2x[s] = gg / (hh * hh); hx[s] = hh;
        out[(size_t)s * NT + t]       = mux[s];
        out[(size_t)(4 + s) * NT + t] = s2x[s];
        out[(size_t)(8 + s) * NT + t] = hh;
    }
    const float sd0 = 1.f / (1.f + __expf(-d0[0]));
    const float sd1 = 1.f / (1.f + __expf(-d1[0]));
    const float sd2 = 1.f / (1.f + __expf(-d2[0]));
    const float c0 = hx[0] * sd0, c1 = hx[1] * sd1, c2 = hx[2] * sd2;
    const float den = c0 + c1 + c2;
    const float muc = mux[0] * c0 + mux[1] * c1 + mux[2] * c2;
    const float sgc = s2x[0] * c0 * c0 + s2x[1] * c1 * c1 + s2x[2] * c2 * c2;
    out[(size_t)3 * NT + t]  = muc / den;
    out[(size_t)7 * NT + t]  = sgc / (den * den);
    out[(size_t)11 * NT + t] = den;
}

extern "C" void kernel_launch(void* const* d_in, const int* in_sizes, int n_in,
                              void* d_out, int out_size, void* d_ws, size_t ws_size,
                              hipStream_t stream) {
    // input order per source i: x=8i, alpha=8i+1, beta=8i+2, sig=8i+3, eta=8i+4, gam=8i+5, w=8i+6, disc=8i+7
    const float* x0 = (const float*)d_in[0];
    const float* x1 = (const float*)d_in[8];
    const float* x2 = (const float*)d_in[16];

    unsigned short* bc = (unsigned short*)d_ws;                  // 512*(512+256+128) ushorts = 917504 B
    float* prmAll = (float*)((char*)d_ws + 917504);              // 3*1280 floats = 15360 B
    float* pws    = (float*)((char*)d_ws + 917504 + 15360);      // 3*4*3*NT floats = 9.44 MB
    float* out = (float*)d_out;

    prep_kernel<<<1536, 128, 0, stream>>>(
        (const float*)d_in[6],  (const float*)d_in[2],  (const float*)d_in[1],
        (const float*)d_in[3],  (const float*)d_in[4],  (const float*)d_in[5],
        (const float*)d_in[14], (const float*)d_in[10], (const float*)d_in[9],
        (const float*)d_in[11], (const float*)d_in[12], (const float*)d_in[13],
        (const float*)d_in[22], (const float*)d_in[18], (const float*)d_in[17],
        (const float*)d_in[19], (const float*)d_in[20], (const float*)d_in[21],
        bc, prmAll);

    const size_t bcoff1 = 512 * 512, bcoff2 = 512 * 512 + 512 * 256;
    fused_src<512><<<2048, 256, 0, stream>>>(x0, bc,          prmAll,        pws);
    fused_src<256><<<2048, 256, 0, stream>>>(x1, bc + bcoff1, prmAll + 1280, pws + (size_t)12 * NT);
    fused_src<128><<<2048, 256, 0, stream>>>(x2, bc + bcoff2, prmAll + 2560, pws + (size_t)24 * NT);
    combine_kernel<<<256, 256, 0, stream>>>(pws, (const float*)d_in[7], (const float*)d_in[15],
                                            (const float*)d_in[23], out);
}

// Round 11
// 148.691 us; speedup vs baseline: 1.5128x; 1.5128x over previous
//
#include <hip/hip_runtime.h>
#include <hip/hip_bf16.h>

typedef __attribute__((ext_vector_type(8))) short short8;
typedef __attribute__((ext_vector_type(4))) float f32x4;

#define NT 65536

__device__ __forceinline__ unsigned short f2bf(float f) {
    union { float f; unsigned int u; } v; v.f = f;
    unsigned int u = v.u;
    unsigned int r = (u + 0x7fffu + ((u >> 16) & 1u)) >> 16;  // RNE
    return (unsigned short)r;
}

__device__ __forceinline__ unsigned int cvt_pk_bf16(float lo, float hi) {
    unsigned int r;
    asm("v_cvt_pk_bf16_f32 %0, %1, %2" : "=v"(r) : "v"(lo), "v"(hi));
    return r;
}

#define LGKM0()  asm volatile("s_waitcnt lgkmcnt(0)" ::: "memory")
#define BAR()    __builtin_amdgcn_s_barrier()
#define SB0()    __builtin_amdgcn_sched_barrier(0)

// ---------------- prep (all 3 sources): bf16 B panel + per-k params ----------------
// Panel row n: k16=n>>5, typ=(n>>4)&1, r=n&15 -> k=k16*16+r; typ0=w, typ1=beta.
// prm per source (5*256 f32): [0:256)=||w_k||^2, [256)=gam^2, [512)=eta^2, [768)=alpha, [1024)=sig^2
__global__ void prep_kernel(const float* __restrict__ w0, const float* __restrict__ b0,
                            const float* __restrict__ a0, const float* __restrict__ s0,
                            const float* __restrict__ e0, const float* __restrict__ g0,
                            const float* __restrict__ w1, const float* __restrict__ b1,
                            const float* __restrict__ a1, const float* __restrict__ s1,
                            const float* __restrict__ e1, const float* __restrict__ g1,
                            const float* __restrict__ w2, const float* __restrict__ b2,
                            const float* __restrict__ a2, const float* __restrict__ s2,
                            const float* __restrict__ e2, const float* __restrict__ g2,
                            unsigned short* __restrict__ bc, float* __restrict__ prmAll) {
    __shared__ float red[2];
    const int bx = blockIdx.x;
    const int s = bx >> 9;            // 0..2
    const int n = bx & 511;           // panel row
    const int P = 512 >> s;
    const float* w   = (s == 0) ? w0 : ((s == 1) ? w1 : w2);
    const float* bet = (s == 0) ? b0 : ((s == 1) ? b1 : b2);
    const float* alp = (s == 0) ? a0 : ((s == 1) ? a1 : a2);
    const float* sig = (s == 0) ? s0 : ((s == 1) ? s1 : s2);
    const float* eta = (s == 0) ? e0 : ((s == 1) ? e1 : e2);
    const float* gam = (s == 0) ? g0 : ((s == 1) ? g1 : g2);
    unsigned short* dstb = bc + ((s == 0) ? 0 : ((s == 1) ? (512 * 512) : (512 * 512 + 512 * 256)));
    float* prm = prmAll + 1280 * s;

    const int tid = threadIdx.x;      // 128
    const int k16 = n >> 5;
    const int typ = (n >> 4) & 1;
    const int k = k16 * 16 + (n & 15);
    const bool isw = (typ == 0);
    const float* src = (isw ? w : bet) + (size_t)k * P;
    unsigned short* dst = dstb + (size_t)n * P;
    float ss = 0.f;
    for (int c = tid; c < P; c += 128) {
        float f = src[c];
        dst[c] = f2bf(f);
        if (isw) ss += f * f;
    }
#pragma unroll
    for (int m = 1; m < 64; m <<= 1) ss += __shfl_xor(ss, m);
    if ((tid & 63) == 0) red[tid >> 6] = ss;
    __syncthreads();
    if (isw && tid == 0) prm[k] = red[0] + red[1];
    if (n == 0) {
        for (int kk = tid; kk < 256; kk += 128) {
            float g = gam[kk], e = eta[kk];
            prm[256 + kk]  = g * g;
            prm[512 + kk]  = e * e;
            prm[768 + kk]  = alp[kk];
            prm[1024 + kk] = sig[kk] * sig[kk];
        }
    }
}

// ---------------- fused per-source: resident-B, tile-distance-prefetch GEMM + epilogue ----------------
// grid 512 (h = b>>8 k-half, rg = b&255), 512 thr (8 waves). Block: 256 x-rows (8 tiles x 32)
// x 128 k's. h-siblings are 256 apart (256%8==0) -> same XCD -> L2/L3 dedup of x.
// Wave wv owns k16 = h*8+wv (16 k's = w-strip + beta-strip); Bf[2][KSW] register-resident
// (256-reg budget at 2 waves/SIMD). x loads for tile t+2 issued at top of tile t's phase
// (distance ~2 tiles); cvt consumes them one tile later (implicit counted vmcnt via reg deps,
// order pinned by sched_barrier). 2 barriers per tile. Swapped MFMA mfma(panel,x):
// k lane-local -> epilogue = register math + 2 shuffles. LDS 16B-slot XOR swizzle (free).
template<int P>
__global__ __launch_bounds__(512, 2)
void fused_src(const float* __restrict__ x, const unsigned short* __restrict__ Bc,
               const float* __restrict__ prm, float* __restrict__ pwsS) {
    constexpr int KSW = P / 32;        // MFMA k-steps (16/8/4)
    constexpr int CPT = P / 64;        // float4 loads per thread per tile (8/4/2)
    constexpr int QPT = (CPT / 2 > 0) ? CPT / 2 : 1;  // uint4 LDS writes per thread
    constexpr int T = 8;

    __shared__ unsigned short Xs[2][32 * P];   // bf16 x tile, dbuf
    __shared__ float xn2[2][32];
    __shared__ float part[8][32][3];

    const int b = blockIdx.x;
    const int h = b >> 8;
    const int rg = b & 255;
    const int rowbase = rg * 256;

    const int tid = threadIdx.x, lane = tid & 63, wv = tid >> 6;
    const int l15 = lane & 15, l4 = lane >> 4;
    const int k16 = h * 8 + wv;

    // staging map: thread -> row = tid>>4 (0..31), span = (tid&15)*(P/16)
    const int srow = tid >> 4;
    const int sc = tid & 15;
    const float* xth = x + (size_t)(rowbase + srow) * P + sc * (P / 16);

    // ---- resident B fragments (A-operand layout: strip-row = l15, k-off = l4*8) ----
    short8 Bf0[KSW], Bf1[KSW];
#pragma unroll
    for (int ks = 0; ks < KSW; ks++) {
        Bf0[ks] = *(const short8*)(Bc + (size_t)(k16 * 32 + l15) * P + ks * 32 + l4 * 8);
        Bf1[ks] = *(const short8*)(Bc + (size_t)(k16 * 32 + 16 + l15) * P + ks * 32 + l4 * 8);
    }

    f32x4 acc00 = {0,0,0,0}, acc01 = {0,0,0,0}, acc10 = {0,0,0,0}, acc11 = {0,0,0,0};
    float4 xr[CPT];

    auto issueX = [&](int t) {
#pragma unroll
        for (int j = 0; j < CPT; j++)
            xr[j] = *(const float4*)(xth + (size_t)t * 32 * P + j * 4);
    };
    auto cvtWrite = [&](int bufp) {
        float s = 0.f;
#pragma unroll
        for (int q = 0; q < QPT; q++) {
            float4 a = xr[2 * q], c = xr[2 * q + 1];
            s += a.x*a.x + a.y*a.y + a.z*a.z + a.w*a.w
               + c.x*c.x + c.y*c.y + c.z*c.z + c.w*c.w;
            uint4 pk = { cvt_pk_bf16(a.x, a.y), cvt_pk_bf16(a.z, a.w),
                         cvt_pk_bf16(c.x, c.y), cvt_pk_bf16(c.z, c.w) };
            const int m = sc * QPT + q;
            *(uint4*)(&Xs[bufp][srow * P + ((m ^ (srow & 7)) << 3)]) = pk;
        }
        s += __shfl_xor(s, 1); s += __shfl_xor(s, 2);
        s += __shfl_xor(s, 4); s += __shfl_xor(s, 8);
        if (sc == 0) xn2[bufp][srow] = s;
    };
    auto compute = [&](int bufp) {
#pragma unroll
        for (int ks = 0; ks < KSW; ks++) {
            const int m = (ks * 4 + l4) ^ (l15 & 7);
            short8 xf0 = *(const short8*)(&Xs[bufp][l15 * P + (m << 3)]);
            short8 xf1 = *(const short8*)(&Xs[bufp][(16 + l15) * P + (m << 3)]);
            acc00 = __builtin_amdgcn_mfma_f32_16x16x32_bf16(Bf0[ks], xf0, acc00, 0, 0, 0);
            acc10 = __builtin_amdgcn_mfma_f32_16x16x32_bf16(Bf1[ks], xf0, acc10, 0, 0, 0);
            acc01 = __builtin_amdgcn_mfma_f32_16x16x32_bf16(Bf0[ks], xf1, acc01, 0, 0, 0);
            acc11 = __builtin_amdgcn_mfma_f32_16x16x32_bf16(Bf1[ks], xf1, acc11, 0, 0, 0);
        }
    };

    // ---- prologue ----
    issueX(0); SB0();
    cvtWrite(0); SB0();
    issueX(1); SB0();

#pragma unroll
    for (int t = 0; t < T; t++) {
        LGKM0(); SB0(); BAR(); SB0();
        if (t + 1 < T) { cvtWrite((t + 1) & 1); SB0(); }
        if (t + 2 < T) { issueX(t + 2); SB0(); }
        compute(t & 1);
        SB0();

        // ---- epilogue for tile t: k = k16*16 + 4*l4 + j (lane-local), x-row = xf*16 + l15
        {
            const int kb = k16 * 16 + 4 * l4;
            const f32x4 wn2 = *(const f32x4*)(prm + kb);
            const f32x4 g2  = *(const f32x4*)(prm + 256 + kb);
            const f32x4 hv  = *(const f32x4*)(prm + 512 + kb);
            const f32x4 alv = *(const f32x4*)(prm + 768 + kb);
            const f32x4 s2v = *(const f32x4*)(prm + 1024 + kb);
#pragma unroll
            for (int xf = 0; xf < 2; xf++) {
                const int xrow = xf * 16 + l15;
                const float xv = xn2[t & 1][xrow];
                const f32x4 aw = xf ? acc01 : acc00;
                const f32x4 ab = xf ? acc11 : acc10;
                float hs = 0.f, ms = 0.f, gs = 0.f;
#pragma unroll
                for (int j = 0; j < 4; j++) {
                    const float d2 = xv - 2.f * aw[j] + wn2[j];
                    const float e  = __expf(-g2[j] * d2);
                    const float ah = e * hv[j];
                    hs += ah;
                    ms += (ab[j] + alv[j]) * ah;
                    gs += s2v[j] * ah * ah;
                }
                hs += __shfl_xor(hs, 16); hs += __shfl_xor(hs, 32);
                ms += __shfl_xor(ms, 16); ms += __shfl_xor(ms, 32);
                gs += __shfl_xor(gs, 16); gs += __shfl_xor(gs, 32);
                if (l4 == 0) {
                    part[wv][xrow][0] = hs;
                    part[wv][xrow][1] = ms;
                    part[wv][xrow][2] = gs;
                }
            }
        }
        LGKM0(); SB0(); BAR(); SB0();
        if (tid < 96) {
            const int v = tid >> 5, r = tid & 31;
            float s = 0.f;
#pragma unroll
            for (int w8 = 0; w8 < 8; w8++) s += part[w8][r][v];
            pwsS[(size_t)(h * 3 + v) * NT + rowbase + t * 32 + r] = s;
        }
        acc00 = (f32x4){0,0,0,0}; acc01 = (f32x4){0,0,0,0};
        acc10 = (f32x4){0,0,0,0}; acc11 = (f32x4){0,0,0,0};
    }
}

// ---------------- combine: all outputs from 2 h-partials per source ----------------
__global__ void combine_kernel(const float* __restrict__ pws,
                               const float* __restrict__ d0, const float* __restrict__ d1,
                               const float* __restrict__ d2, float* __restrict__ out) {
    const int t = blockIdx.x * 256 + threadIdx.x;
    float mux[3], s2x[3], hx[3];
#pragma unroll
    for (int s = 0; s < 3; s++) {
        const float* bb = pws + (size_t)s * 6 * NT;
        const float hh = bb[t] + bb[(size_t)3 * NT + t];
        const float mm = bb[(size_t)1 * NT + t] + bb[(size_t)4 * NT + t];
        const float gg = bb[(size_t)2 * NT + t] + bb[(size_t)5 * NT + t];
        mux[s] = mm / hh; s2x[s] = gg / (hh * hh); hx[s] = hh;
        out[(size_t)s * NT + t]       = mux[s];
        out[(size_t)(4 + s) * NT + t] = s2x[s];
        out[(size_t)(8 + s) * NT + t] = hh;
    }
    const float sd0 = 1.f / (1.f + __expf(-d0[0]));
    const float sd1 = 1.f / (1.f + __expf(-d1[0]));
    const float sd2 = 1.f / (1.f + __expf(-d2[0]));
    const float c0 = hx[0] * sd0, c1 = hx[1] * sd1, c2 = hx[2] * sd2;
    const float den = c0 + c1 + c2;
    const float muc = mux[0] * c0 + mux[1] * c1 + mux[2] * c2;
    const float sgc = s2x[0] * c0 * c0 + s2x[1] * c1 * c1 + s2x[2] * c2 * c2;
    out[(size_t)3 * NT + t]  = muc / den;
    out[(size_t)7 * NT + t]  = sgc / (den * den);
    out[(size_t)11 * NT + t] = den;
}

extern "C" void kernel_launch(void* const* d_in, const int* in_sizes, int n_in,
                              void* d_out, int out_size, void* d_ws, size_t ws_size,
                              hipStream_t stream) {
    // input order per source i: x=8i, alpha=8i+1, beta=8i+2, sig=8i+3, eta=8i+4, gam=8i+5, w=8i+6, disc=8i+7
    const float* x0 = (const float*)d_in[0];
    const float* x1 = (const float*)d_in[8];
    const float* x2 = (const float*)d_in[16];

    unsigned short* bc = (unsigned short*)d_ws;                  // 512*(512+256+128) ushorts = 917504 B
    float* prmAll = (float*)((char*)d_ws + 917504);              // 3*1280 floats = 15360 B
    float* pws    = (float*)((char*)d_ws + 917504 + 15360);      // 18*NT floats = 4.72 MB
    float* out = (float*)d_out;

    prep_kernel<<<1536, 128, 0, stream>>>(
        (const float*)d_in[6],  (const float*)d_in[2],  (const float*)d_in[1],
        (const float*)d_in[3],  (const float*)d_in[4],  (const float*)d_in[5],
        (const float*)d_in[14], (const float*)d_in[10], (const float*)d_in[9],
        (const float*)d_in[11], (const float*)d_in[12], (const float*)d_in[13],
        (const float*)d_in[22], (const float*)d_in[18], (const float*)d_in[17],
        (const float*)d_in[19], (const float*)d_in[20], (const float*)d_in[21],
        bc, prmAll);

    const size_t bcoff1 = 512 * 512, bcoff2 = 512 * 512 + 512 * 256;
    fused_src<512><<<512, 512, 0, stream>>>(x0, bc,          prmAll,        pws);
    fused_src<256><<<512, 512, 0, stream>>>(x1, bc + bcoff1, prmAll + 1280, pws + (size_t)6 * NT);
    fused_src<128><<<512, 512, 0, stream>>>(x2, bc + bcoff2, prmAll + 2560, pws + (size_t)12 * NT);
    combine_kernel<<<256, 256, 0, stream>>>(pws, (const float*)d_in[7], (const float*)d_in[15],
                                            (const float*)d_in[23], out);
}